// Round 1
// 290.972 us; speedup vs baseline: 1.0438x; 1.0438x over previous
//
#include <hip/hip_runtime.h>
#include <math.h>

constexpr int Nn = 64, Cc = 64, Tt = 300, Vv = 25, Ff = 64;
constexpr int TP = Tt / 2;             // 150 t-pairs per n
constexpr float ALPHA = 0.2f;
constexpr float NEG_INF = -9.0e15f;

__global__ __launch_bounds__(256, 4) void gat_kernel(
    const float* __restrict__ x,    // (N,C,T,V)
    const int*   __restrict__ adj,  // (V,V)
    const float* __restrict__ W,    // (C,F)
    const float* __restrict__ a,    // (2F,1)
    float* __restrict__ out)        // (N,F,T,V)
{
    __shared__ float xs[2][Cc][32];        // 16384 B  x staged, stride 32
    __shared__ float hs[2][Vv][68];        // 13600 B  h[v][f], stride 68 (b128-friendly)
    __shared__ float attT[2][Vv][32];      // 6400 B   att transposed [j][i]
    __shared__ float fpart[2][4][32][2];   // 2048 B   per-wave f1/f2 partials
    __shared__ unsigned adjm[Vv];

    const int tid = threadIdx.x;
    const int blk = blockIdx.x;            // n*TP + tp
    const int n = blk / TP, tp = blk - n * TP;
    const int t0 = tp * 2;

    // ---- staging: x slice (2 t's, all c) -> LDS; adj row bitmasks ----
    {
        const float* xb = x + (size_t)n * Cc * Tt * Vv + (size_t)t0 * Vv;
        const int j = tid & 63, cg = tid >> 6;
        const int pp = (j >= Vv) ? 1 : 0;
        const int vj = j - Vv * pp;
        if (j < 2 * Vv) {
            #pragma unroll
            for (int i = 0; i < 16; ++i) {
                const int c = i * 4 + cg;
                xs[pp][c][vj] = xb[(size_t)c * (Tt * Vv) + j];
            }
        }
    }
    if (tid >= 128 && tid < 128 + Vv) {
        const int i = tid - 128;
        unsigned m = 0;
        #pragma unroll
        for (int j = 0; j < Vv; ++j) m |= (adj[i * Vv + j] > 0 ? 1u : 0u) << j;
        adjm[i] = m;
    }
    __syncthreads();

    // wave = one 16-wide f-slice; lanes = (p, v): lane 0-24 -> t0, 32-56 -> t0+1
    const int wid  = tid >> 6;
    const int lane = tid & 63;
    const int ph   = lane >> 5;            // which t of the pair
    const int v    = lane & 31;            // active v < 25
    const int f0   = __builtin_amdgcn_readfirstlane(wid << 4);  // wave-uniform f base

    // ---- Phase B: acc[k] = sum_c x[c][v] * W[c][f0+k]; W via SGPR s_load ----
    float acc[16];
    #pragma unroll
    for (int k = 0; k < 16; ++k) acc[k] = 0.f;

    const float* __restrict__ Wg = W + f0;     // wave-uniform pointer
    const float* xcol = &xs[ph][0][v];         // per-lane, stride 32 floats per c
    #pragma unroll 4
    for (int c = 0; c < Cc; ++c) {
        const float xv = xcol[c * 32];         // 4 B LDS per 16 FMAs
        float wv[16];
        *(float4*)&wv[0]  = *(const float4*)(Wg + c * Ff + 0);   // s_load_dwordx4
        *(float4*)&wv[4]  = *(const float4*)(Wg + c * Ff + 4);
        *(float4*)&wv[8]  = *(const float4*)(Wg + c * Ff + 8);
        *(float4*)&wv[12] = *(const float4*)(Wg + c * Ff + 12);
        #pragma unroll
        for (int k = 0; k < 16; ++k) acc[k] += xv * wv[k];
    }

    // ---- Phase C: register-local partial dots with a1/a2 (SGPR-resident) ----
    float p1 = 0.f, p2 = 0.f;
    #pragma unroll
    for (int k = 0; k < 16; ++k) {
        p1 += acc[k] * a[f0 + k];
        p2 += acc[k] * a[Ff + f0 + k];
    }

    if (v < Vv) {
        #pragma unroll
        for (int q = 0; q < 4; ++q) {
            float4 t4;
            t4.x = acc[q * 4 + 0]; t4.y = acc[q * 4 + 1];
            t4.z = acc[q * 4 + 2]; t4.w = acc[q * 4 + 3];
            *(float4*)&hs[ph][v][f0 + q * 4] = t4;
        }
        *(float2*)&fpart[ph][wid][v][0] = make_float2(p1, p2);
    }
    __syncthreads();

    // ---- Phase D: 50 lanes of wave 0 do both problems' softmax rows ----
    if (tid < 2 * Vv) {
        const int dp = (tid >= Vv) ? 1 : 0;
        const int i = tid - Vv * dp;
        float f1 = 0.f, f2 = 0.f;
        #pragma unroll
        for (int w = 0; w < 4; ++w) {
            const float2 fp = *(const float2*)&fpart[dp][w][i][0];
            f1 += fp.x; f2 += fp.y;
        }
        const unsigned m = adjm[i];
        float ev[Vv];
        float mx = -INFINITY;
        #pragma unroll
        for (int j = 0; j < Vv; ++j) {
            const float f2j = __shfl(f2, dp * Vv + j, 64);  // f2[j] lives in lane dp*25+j
            float z = f1 + f2j;
            z = (z > 0.f) ? z : ALPHA * z;                  // leaky_relu BEFORE mask
            z = ((m >> j) & 1u) ? z : NEG_INF;
            ev[j] = z; mx = fmaxf(mx, z);
        }
        float s = 0.f;
        #pragma unroll
        for (int j = 0; j < Vv; ++j) { const float e = __expf(ev[j] - mx); ev[j] = e; s += e; }
        const float inv = 1.f / s;
        #pragma unroll
        for (int j = 0; j < Vv; ++j) attT[dp][j][i] = ev[j] * inv;
    }
    __syncthreads();

    // ---- Phase E: h'[v][f-slice] = sum_j att[v][j] * h[j][f-slice] ----
    float acc2[16];
    #pragma unroll
    for (int k = 0; k < 16; ++k) acc2[k] = 0.f;
    const float* attb = &attT[ph][0][v];
    #pragma unroll 5
    for (int j = 0; j < Vv; ++j) {
        const float av = attb[j * 32];                       // lane-contiguous, conflict-free
        float hv[16];                                        // half-wave-uniform broadcast reads
        *(float4*)&hv[0]  = *(const float4*)&hs[ph][j][f0 + 0];
        *(float4*)&hv[4]  = *(const float4*)&hs[ph][j][f0 + 4];
        *(float4*)&hv[8]  = *(const float4*)&hs[ph][j][f0 + 8];
        *(float4*)&hv[12] = *(const float4*)&hs[ph][j][f0 + 12];
        #pragma unroll
        for (int k = 0; k < 16; ++k) acc2[k] += av * hv[k];
    }

    // ---- Phase F: elu + direct register->global writeout (200 B contiguous/store) ----
    if (v < Vv) {
        float* ob = out + ((size_t)(n * Ff + f0) * Tt + (size_t)(t0 + ph)) * Vv + v;
        #pragma unroll
        for (int k = 0; k < 16; ++k) {
            float z = acc2[k];
            z = (z > 0.f) ? z : (__expf(z) - 1.f);   // elu(alpha=1)
            ob[(size_t)k * Tt * Vv] = z;
        }
    }
}

extern "C" void kernel_launch(void* const* d_in, const int* in_sizes, int n_in,
                              void* d_out, int out_size, void* d_ws, size_t ws_size,
                              hipStream_t stream) {
    const float* x   = (const float*)d_in[0];
    const int*   adj = (const int*)d_in[1];
    const float* W   = (const float*)d_in[2];
    const float* a   = (const float*)d_in[3];
    float* out = (float*)d_out;

    dim3 grid(Nn * TP);     // 9600 blocks, 2 (n,t) problems each
    dim3 block(256);
    gat_kernel<<<grid, block, 0, stream>>>(x, adj, W, a, out);
}